// Round 4
// baseline (1609.004 us; speedup 1.0000x reference)
//
#include <hip/hip_runtime.h>

typedef unsigned short ushort_t;
typedef short bf16x8 __attribute__((ext_vector_type(8)));
typedef float f32x4 __attribute__((ext_vector_type(4)));

#define H 1900
#define FH 7600      // 4*H
#define BATCH 8192
#define KP 1952      // padded K stride for hbf/wmhT (gemmA operands)
#define NP_A 1920    // padded N for gemmA (m columns)
#define NB 7680      // padded row count of whxT
#define BK 32
#define KITERS (KP / BK)   // 61

// gemmB tiled-layout geometry: panel = 256 rows; K split into 30 full 64-tiles + 32 tail
#define NKT 30
#define KT_U 16384         // ushorts per full K-tile slab (256*64)
#define TAIL_U 491520      // NKT*KT_U : offset of tail slab (256*32)
#define PANEL_U 499712     // TAIL_U + 256*32 : ushorts per panel

// ---- ws layout (bytes) ----
static const size_t OFF_SWX  = 0;          // 7600 f32
static const size_t OFF_SWH  = 32768;      // 7600 f32
static const size_t OFF_SWMX = 65536;      // 1900 f32
static const size_t OFF_SWMH = 73728;      // 1900 f32
static const size_t OFF_WMXN = 81920;      // 10*1920 f32 (pre-scaled wmx_n)
static const size_t OFF_PART = 163840;     // partial colsums: 8*(7600+7600+1900+1900) f32
static const size_t OFF_HBF  = 786432;                   // h_prev bf16 [8192][1952] (KP layout)
static const size_t OFF_MEXT = OFF_HBF + 31981568;       // m_ext bf16 TILED: 32 panels * PANEL_U
static const size_t OFF_WMHT = OFF_MEXT + 31981568;      // wmh_n^T bf16 [1920][1952] (KP layout)
static const size_t OFF_WHXT = OFF_WMHT + 7495680;       // whxT bf16 TILED: 30 panels * PANEL_U
// end = OFF_WHXT + 29982720 ≈ 97.5 MB

// partial-sum sub-offsets (in floats, within OFF_PART)
#define PW_X  0
#define PW_H  60800
#define PW_MX 121600
#define PW_MH 136800

#define BAR() __builtin_amdgcn_s_barrier()
#define PRIO1 __builtin_amdgcn_s_setprio(1)
#define PRIO0 __builtin_amdgcn_s_setprio(0)
#define SB0() __builtin_amdgcn_sched_barrier(0)
#define WAIT_LGKM(N) asm volatile("s_waitcnt lgkmcnt(" #N ")" ::: "memory")
#define WAIT_VM(N) asm volatile("s_waitcnt vmcnt(" #N ")" ::: "memory")

__device__ __forceinline__ ushort_t f2bf(float x) {
  unsigned u = __float_as_uint(x);
  return (ushort_t)((u + 0x7fffu + ((u >> 16) & 1u)) >> 16);
}

// async global->LDS, 16 B per lane; LDS dest = wave-uniform base (+ lane*16 by HW)
__device__ __forceinline__ void gl_lds16(const ushort_t* g, ushort_t* lds) {
  __builtin_amdgcn_global_load_lds(
      (const __attribute__((address_space(1))) unsigned int*)(g),
      (__attribute__((address_space(3))) unsigned int*)(lds), 16, 0, 0);
}

// tiled-layout address helpers (row within 256-row panels)
__device__ __forceinline__ size_t tiled_addr(int row, int col) {
  // col in [0,1920)
  return (size_t)(row >> 8) * PANEL_U + (size_t)(col >> 6) * KT_U +
         (size_t)(row & 255) * 64 + (col & 63);
}
__device__ __forceinline__ size_t tiled_addr_tail(int row, int ctail) {
  // ctail in [0,32) = col-1920
  return (size_t)(row >> 8) * PANEL_U + TAIL_U + (size_t)(row & 255) * 32 + ctail;
}

// ---------------- scales: per-column l2-norm partials, then gain*rsqrt ----------------
__global__ void colsum_partial_kernel(const float* __restrict__ wx, const float* __restrict__ wh,
                                      const float* __restrict__ wmx, const float* __restrict__ wmh,
                                      float* __restrict__ parts) {
  int c = blockIdx.x * 256 + threadIdx.x;
  int y = blockIdx.y, p = blockIdx.z;
  const float* W; int K, N; float* out;
  if (y == 0)      { W = wx;  K = 10;   N = FH; out = parts + PW_X  + (size_t)p * FH; }
  else if (y == 1) { W = wh;  K = 1900; N = FH; out = parts + PW_H  + (size_t)p * FH; }
  else if (y == 2) { W = wmx; K = 10;   N = H;  out = parts + PW_MX + (size_t)p * H;  }
  else             { W = wmh; K = 1900; N = H;  out = parts + PW_MH + (size_t)p * H;  }
  if (c >= N) return;
  int rp = (K + 7) / 8;
  int r0 = p * rp, r1 = r0 + rp; if (r1 > K) r1 = K;
  float s = 0.f;
  for (int r = r0; r < r1; ++r) { float v = W[(size_t)r * N + c]; s += v * v; }
  out[c] = s;
}

__global__ void scales_final_kernel(const float* __restrict__ parts,
                                    const float* __restrict__ gx, const float* __restrict__ gh,
                                    const float* __restrict__ gmx, const float* __restrict__ gmh,
                                    float* __restrict__ s_wx, float* __restrict__ s_wh,
                                    float* __restrict__ s_wmx, float* __restrict__ s_wmh) {
  int c = blockIdx.x * 256 + threadIdx.x;
  int y = blockIdx.y;
  const float* pp; int N; const float* g; float* out;
  if (y == 0)      { pp = parts + PW_X;  N = FH; g = gx;  out = s_wx;  }
  else if (y == 1) { pp = parts + PW_H;  N = FH; g = gh;  out = s_wh;  }
  else if (y == 2) { pp = parts + PW_MX; N = H;  g = gmx; out = s_wmx; }
  else             { pp = parts + PW_MH; N = H;  g = gmh; out = s_wmh; }
  if (c >= N) return;
  float s = 0.f;
  for (int p = 0; p < 8; ++p) s += pp[(size_t)p * N + c];
  out[c] = g[c] * rsqrtf(fmaxf(s, 1e-12f));
}

// ---------------- conversions ----------------
__global__ void cvt_h_kernel(const float* __restrict__ h_prev, ushort_t* __restrict__ hbf) {
  size_t idx = (size_t)blockIdx.x * 256 + threadIdx.x;   // < 8192*1952
  int row = (int)(idx / KP), col = (int)(idx % KP);
  float v = (col < H) ? h_prev[(size_t)row * H + col] : 0.f;
  hbf[idx] = f2bf(v);
}

__global__ void wmxn_kernel(const float* __restrict__ wmx, const float* __restrict__ s_wmx,
                            float* __restrict__ wmxn) {
  int idx = blockIdx.x * 256 + threadIdx.x;  // < 19200
  int i = idx / NP_A, j = idx - i * NP_A;
  wmxn[idx] = (j < H) ? wmx[i * H + j] * s_wmx[j] : 0.f;
}

// wmh [1900][1900] -> wmhT [1920][1952] bf16, transposed, pre-scaled (KP layout, gemmA operand)
__global__ void wmhT_kernel(const float* __restrict__ wmh, const float* __restrict__ s_wmh,
                            ushort_t* __restrict__ wmhT) {
  __shared__ float tile[32][33];
  int n0 = blockIdx.x * 32, k0 = blockIdx.y * 32;
  int tx = threadIdx.x & 31, ty = threadIdx.x >> 5;   // ty 0..7
#pragma unroll
  for (int it = 0; it < 4; ++it) {
    int k = k0 + ty + it * 8, n = n0 + tx;
    float v = (k < H && n < H) ? wmh[(size_t)k * H + n] : 0.f;
    tile[ty + it * 8][tx] = v;   // tile[k_local][n_local]
  }
  __syncthreads();
#pragma unroll
  for (int it = 0; it < 4; ++it) {
    int n = n0 + ty + it * 8, k = k0 + tx;
    float v = tile[tx][ty + it * 8];
    float s = (n < H) ? s_wmh[n] : 0.f;
    wmhT[(size_t)n * KP + k] = f2bf(v * s);
  }
}

// wh [1900][7600] + wx [10][7600] -> whxT TILED [30 panels]: row n=4j+g <- col c=g*1900+j,
// k<1900: wh_n ; 1920<=k<1930: wx_n ; else 0. Pre-scaled.
__global__ void whxT_kernel(const float* __restrict__ wh, const float* __restrict__ wx,
                            const float* __restrict__ s_wh, const float* __restrict__ s_wx,
                            ushort_t* __restrict__ whxT) {
  __shared__ float tile[32][33];
  int c0 = blockIdx.x * 32, k0 = blockIdx.y * 32;
  int tx = threadIdx.x & 31, ty = threadIdx.x >> 5;
#pragma unroll
  for (int it = 0; it < 4; ++it) {
    int k = k0 + ty + it * 8, c = c0 + tx;
    float v = 0.f;
    if (c < FH) {
      if (k < H) v = wh[(size_t)k * FH + c] * s_wh[c];
      else if (k >= NP_A && k < NP_A + 10) v = wx[(size_t)(k - NP_A) * FH + c] * s_wx[c];
    }
    tile[ty + it * 8][tx] = v;   // tile[k_local][c_local]
  }
  __syncthreads();
#pragma unroll
  for (int it = 0; it < 4; ++it) {
    int c = c0 + ty + it * 8, k = k0 + tx;
    if (c < FH) {
      int g = c / H; int j = c - g * H; int n = 4 * j + g;
      size_t a = (k < NP_A) ? tiled_addr(n, k) : tiled_addr_tail(n, k - NP_A);
      whxT[a] = f2bf(tile[tx][ty + it * 8]);
    }
  }
}

__global__ void mext_tail_kernel(const float* __restrict__ inputs, ushort_t* __restrict__ m_ext) {
  int idx = blockIdx.x * 256 + threadIdx.x;   // < 8192*32
  int row = idx >> 5, c = idx & 31;
  float v = (c < 10) ? inputs[(size_t)row * 10 + c] : 0.f;
  m_ext[tiled_addr_tail(row, c)] = f2bf(v);
}

__global__ void whxT_tail_kernel(ushort_t* __restrict__ whxT) {
  int idx = blockIdx.x * 256 + threadIdx.x;   // < 80*1952
  int n = 7600 + idx / 1952, k = idx % 1952;
  size_t a = (k < NP_A) ? tiled_addr(n, k) : tiled_addr_tail(n, k - NP_A);
  whxT[a] = 0;
}

// ============ gemmA core: 128x128 tile, BK=32, single-buffer (round-0 proven) ============
__device__ __forceinline__ void gemm_tile128(const ushort_t* __restrict__ Ag,
                                             const ushort_t* __restrict__ Bg,
                                             int m0, int n0,
                                             ushort_t* As, ushort_t* Bs,
                                             f32x4 acc[4][4]) {
  const int tid = threadIdx.x;
  const int lane = tid & 63;
  const int quad = lane >> 4;
  const int lo = lane & 15;
  const int wave = tid >> 6;
  const int wm = (wave & 1) << 6;
  const int wn = (wave >> 1) << 6;
  const int sw = (lo >> 1) & 3;

  const int cr = lane >> 2;
  const int hg = (lane & 3) ^ ((lane >> 3) & 3);
  const int r0 = wave * 16 + cr;
  const int r1 = 64 + wave * 16 + cr;
  const ushort_t* gA0 = Ag + (size_t)(m0 + r0) * KP + hg * 8;
  const ushort_t* gA1 = Ag + (size_t)(m0 + r1) * KP + hg * 8;
  const ushort_t* gB0 = Bg + (size_t)(n0 + r0) * KP + hg * 8;
  const ushort_t* gB1 = Bg + (size_t)(n0 + r1) * KP + hg * 8;
  ushort_t* lA0 = As + (wave * 16) * BK;
  ushort_t* lA1 = As + (64 + wave * 16) * BK;
  ushort_t* lB0 = Bs + (wave * 16) * BK;
  ushort_t* lB1 = Bs + (64 + wave * 16) * BK;

  for (int kt = 0; kt < KITERS; ++kt) {
    __syncthreads();
    gl_lds16(gA0, lA0);
    gl_lds16(gA1, lA1);
    gl_lds16(gB0, lB0);
    gl_lds16(gB1, lB1);
    __syncthreads();
    bf16x8 af[4], bfv[4];
#pragma unroll
    for (int mf = 0; mf < 4; ++mf)
      af[mf] = *(const bf16x8*)(As + (wm + mf * 16 + lo) * BK + ((quad ^ sw) << 3));
#pragma unroll
    for (int nf = 0; nf < 4; ++nf)
      bfv[nf] = *(const bf16x8*)(Bs + (wn + nf * 16 + lo) * BK + ((quad ^ sw) << 3));
#pragma unroll
    for (int mf = 0; mf < 4; ++mf)
#pragma unroll
      for (int nf = 0; nf < 4; ++nf)
        acc[mf][nf] = __builtin_amdgcn_mfma_f32_16x16x32_bf16(af[mf], bfv[nf], acc[mf][nf], 0, 0, 0);
    gA0 += BK; gA1 += BK; gB0 += BK; gB1 += BK;
  }
}

// GEMM-A: P = h_prev_bf @ wmh_n^T ; epilogue m = (inputs·wmx_n) * P -> m_ext (TILED)
__global__ void __launch_bounds__(256) gemmA_kernel(const ushort_t* __restrict__ hbf,
                                                    const ushort_t* __restrict__ wmhT,
                                                    const float* __restrict__ inputs,
                                                    const float* __restrict__ wmxn,
                                                    ushort_t* __restrict__ m_ext) {
  __shared__ __align__(16) char smem[16384];
  ushort_t* As = (ushort_t*)smem;
  ushort_t* Bs = (ushort_t*)(smem + 8192);
  f32x4 acc[4][4];
  f32x4 zv = {0.f, 0.f, 0.f, 0.f};
#pragma unroll
  for (int a = 0; a < 4; ++a)
#pragma unroll
    for (int bq = 0; bq < 4; ++bq) acc[a][bq] = zv;
  int m0 = blockIdx.x * 128, n0 = blockIdx.y * 128;
  gemm_tile128(hbf, wmhT, m0, n0, As, Bs, acc);
  __syncthreads();
  float* inL  = (float*)smem;            // [128][10]
  float* wmxL = (float*)(smem + 5120);   // [10][128]
  for (int t = threadIdx.x; t < 1280; t += 256) {
    int r = t / 10, i = t - r * 10;
    inL[t] = inputs[(size_t)(m0 + r) * 10 + i];
  }
  for (int t = threadIdx.x; t < 1280; t += 256) {
    int i = t >> 7, c = t & 127;
    wmxL[t] = wmxn[i * NP_A + n0 + c];
  }
  __syncthreads();
  const int lane = threadIdx.x & 63, quad = lane >> 4, lo = lane & 15;
  const int wave = threadIdx.x >> 6, wm = (wave & 1) << 6, wn = (wave >> 1) << 6;
#pragma unroll
  for (int mf = 0; mf < 4; ++mf)
#pragma unroll
    for (int r = 0; r < 4; ++r) {
      int rl = wm + mf * 16 + quad * 4 + r;
      float inrow[10];
#pragma unroll
      for (int i = 0; i < 10; ++i) inrow[i] = inL[rl * 10 + i];
#pragma unroll
      for (int nf = 0; nf < 4; ++nf) {
        int cl = wn + nf * 16 + lo;
        float mx = 0.f;
#pragma unroll
        for (int i = 0; i < 10; ++i) mx += inrow[i] * wmxL[i * 128 + cl];
        float mv = acc[mf][nf][r] * mx;
        m_ext[tiled_addr(m0 + rl, n0 + cl)] = f2bf(mv);
      }
    }
}

// ============ gemmB: 256x256 tile, BK=64, 8 waves — 3-barrier/2-segment counted schedule ====
// TILED operands (contiguous 16KB bursts per stage_half); LDS 16B-slot XOR swizzle s^(r&7).
//
// Per K-tile T (cur = buf[T&1]; tile T+2 staged into cur after its readers finish):
//   G1: read A(mh0) 8 + B(nh0) 4 + B(nh1) 4  |  G2: read A(mh1) 8   (issue pinned G1<G2)
//   lgkmcnt(8)  -> 32 MFMA (Q00,Q01)
//   BAR-mid     (all B reads + A(mh0) CU-wide done) -> stage B0,B1(T+2)->cur
//   lgkmcnt(0)  -> 32 MFMA (Q11,Q10)
//   BAR-end     (all A reads CU-wide done) -> stage A0,A1(T+2)->cur
//   vmcnt(8)    (newest 8 = T+2's; forces T+1 fully resident)
//   BAR-tb
// Hazards: B regions last read in G1 (stage after BAR-mid OK); A regions last read by
// lgkmcnt(0) before BAR-end (stage after BAR-end OK); tile residency via vmcnt(8)+BAR-tb.

__device__ __forceinline__ void stage_half(const ushort_t* __restrict__ Gp, int rbase, int kt,
                                           ushort_t* L, int tid) {
  const int wave = tid >> 6;
#pragma unroll
  for (int q = 0; q < 2; ++q) {
    const int idx = q * 512 + tid;
    const int r = idx >> 3, s = idx & 7;
    const int gs = s ^ (r & 7);
    gl_lds16(Gp + (size_t)kt * KT_U + (size_t)(rbase + r) * 64 + gs * 8,
             L + (size_t)(q * 512 + wave * 64) * 8);
  }
}

__device__ __forceinline__ void stage_tail(const ushort_t* __restrict__ Gp, ushort_t* L, int tid) {
  const int wave = tid >> 6;
#pragma unroll
  for (int q = 0; q < 2; ++q) {
    const int idx = q * 512 + tid;
    const int r = idx >> 2, s = idx & 3;
    const int gs = s ^ (r & 3);
    gl_lds16(Gp + TAIL_U + (size_t)r * 32 + gs * 8,
             L + (size_t)(q * 512 + wave * 64) * 8);
  }
}

__device__ __forceinline__ void read_Ahalf(const ushort_t* A, int wmL, int lo, int mh,
                                           int sw0, int sw1, bf16x8 af[8]) {
#pragma unroll
  for (int mf = 0; mf < 4; ++mf) {
    const ushort_t* p = A + ((wmL + mh * 64 + mf * 16 + lo) << 6);
    af[mf * 2 + 0] = *(const bf16x8*)(p + sw0);
    af[mf * 2 + 1] = *(const bf16x8*)(p + sw1);
  }
}

__device__ __forceinline__ void read_Bhalf(const ushort_t* B, int wnL, int lo, int nh,
                                           int sw0, int sw1, bf16x8 bf[4]) {
#pragma unroll
  for (int nf = 0; nf < 2; ++nf) {
    const ushort_t* p = B + ((wnL + nh * 32 + nf * 16 + lo) << 6);
    bf[nf * 2 + 0] = *(const bf16x8*)(p + sw0);
    bf[nf * 2 + 1] = *(const bf16x8*)(p + sw1);
  }
}

__device__ __forceinline__ void mfma_quad(const bf16x8 af[8], const bf16x8 bf[4],
                                          f32x4 acc[8][4], int mh, int nh) {
#pragma unroll
  for (int mf = 0; mf < 4; ++mf)
#pragma unroll
    for (int nf = 0; nf < 2; ++nf) {
      f32x4 c = acc[mh * 4 + mf][nh * 2 + nf];
      c = __builtin_amdgcn_mfma_f32_16x16x32_bf16(af[mf * 2 + 0], bf[nf * 2 + 0], c, 0, 0, 0);
      c = __builtin_amdgcn_mfma_f32_16x16x32_bf16(af[mf * 2 + 1], bf[nf * 2 + 1], c, 0, 0, 0);
      acc[mh * 4 + mf][nh * 2 + nf] = c;
    }
}

// MODE: 0=steady (stage T+2, vmcnt(8)); 1=T=NKT-2 (no stage, vmcnt(0)); 2=last (stage tail)
template <int MODE>
__device__ __forceinline__ void b8_tile(const ushort_t* __restrict__ Ap,
                                        const ushort_t* __restrict__ Bp,
                                        int T,
                                        ushort_t* Acur, ushort_t* Bcur,
                                        ushort_t* tailA, ushort_t* tailB,
                                        int tid, int lo, int wmL, int wnL,
                                        int sw0, int sw1, f32x4 acc[8][4]) {
  bf16x8 a0[8], a1[8], b0f[4], b1f[4];
  // G1: A(mh0) + B(nh0) + B(nh1)  (16 x ds_read_b128)
  read_Ahalf(Acur, wmL, lo, 0, sw0, sw1, a0);
  read_Bhalf(Bcur, wnL, lo, 0, sw0, sw1, b0f);
  read_Bhalf(Bcur, wnL, lo, 1, sw0, sw1, b1f);
  SB0();                      // pin: G1 issues strictly before G2 (counted lgkm soundness)
  // G2: A(mh1)  (8 x ds_read_b128)
  read_Ahalf(Acur, wmL, lo, 1, sw0, sw1, a1);
  SB0();
  WAIT_LGKM(8);               // G1 complete; G2 may still fly
  SB0();                      // rule-18: keep MFMA below the wait
  PRIO1;
  mfma_quad(a0, b0f, acc, 0, 0);
  mfma_quad(a0, b1f, acc, 0, 1);
  PRIO0;
  BAR();                      // all B reads + A(mh0) CU-wide done
  if (MODE == 0) {
    stage_half(Bp, 0,   T + 2, Bcur, tid);
    stage_half(Bp, 128, T + 2, Bcur + 8192, tid);
  } else if (MODE == 2) {
    stage_tail(Ap, tailA, tid);
  }
  WAIT_LGKM(0);               // G2 complete
  SB0();
  PRIO1;
  mfma_quad(a1, b1f, acc, 1, 1);
  mfma_quad(a1, b0f, acc, 1, 0);
  PRIO0;
  BAR();                      // all A reads CU-wide done
  if (MODE == 0) {
    stage_half(Ap, 0,   T + 2, Acur, tid);
    stage_half(Ap, 128, T + 2, Acur + 8192, tid);
    WAIT_VM(8);               // newest 8 = T+2's stages -> T+1 fully resident
  } else if (MODE == 1) {
    WAIT_VM(0);
  } else {
    stage_tail(Bp, tailB, tid);
    WAIT_VM(0);
  }
  BAR();                      // tile boundary
}

__global__ void __launch_bounds__(512, 2)
gemmB8_kernel(const ushort_t* __restrict__ mext, const ushort_t* __restrict__ whxT,
              const float* __restrict__ bvec, const float* __restrict__ c_prev,
              float* __restrict__ hout, float* __restrict__ cout) {
  extern __shared__ __align__(16) char smem[];
  ushort_t* As0 = (ushort_t*)smem;                 // buf0 A [256][64]
  ushort_t* Bs0 = (ushort_t*)(smem + 32768);       // buf0 B
  ushort_t* As1 = (ushort_t*)(smem + 65536);       // buf1 A
  ushort_t* Bs1 = (ushort_t*)(smem + 98304);       // buf1 B

  const int tid = threadIdx.x;
  const int lane = tid & 63;
  const int lo = lane & 15, quad = lane >> 4;
  const int wave = tid >> 6;
  const int wmL = (wave & 1) << 7;     // 0 / 128
  const int wnL = (wave >> 1) << 6;    // 0 / 64 / 128 / 192
  const int sw0 = ((quad ^ (lo & 7)) << 3);
  const int sw1 = (((4 | quad) ^ (lo & 7)) << 3);

  // XCD panel-ownership mapping: XCD x owns mt in [(x&3)*8, +8), nt in [(x>>2)*15, +15).
  // mt-minor traversal -> 32 concurrent blocks/XCD cover 8mt x 4nt: A shared 4x, B shared 8x.
  int bid = blockIdx.x;
  int xcd = bid & 7, jj = bid >> 3;           // jj in [0,120)
  int mt = ((xcd & 3) << 3) | (jj & 7);       // [0,32)
  int nt = (xcd >> 2) * 15 + (jj >> 3);       // [0,30)
  int m0 = mt << 8, n0 = nt << 8;

  f32x4 acc[8][4];
  f32x4 zv = {0.f, 0.f, 0.f, 0.f};
#pragma unroll
  for (int a = 0; a < 8; ++a)
#pragma unroll
    for (int bq = 0; bq < 4; ++bq) acc[a][bq] = zv;

  const ushort_t* Ap = mext + (size_t)mt * PANEL_U;
  const ushort_t* Bp = whxT + (size_t)nt * PANEL_U;

  // prologue: tiles 0 -> buf0, 1 -> buf1; vmcnt(8) leaves tile-1's 8 in flight
  stage_half(Ap, 0,   0, As0,        tid);
  stage_half(Ap, 128, 0, As0 + 8192, tid);
  stage_half(Bp, 0,   0, Bs0,        tid);
  stage_half(Bp, 128, 0, Bs0 + 8192, tid);
  stage_half(Ap, 0,   1, As1,        tid);
  stage_half(Ap, 128, 1, As1 + 8192, tid);
  stage_half(Bp, 0,   1, Bs1,        tid);
  stage_half(Bp, 128, 1, Bs1 + 8192, tid);
  WAIT_VM(8);
  BAR();

  for (int T = 0; T < NKT - 2; T += 2) {
    b8_tile<0>(Ap, Bp, T,     As0, Bs0, As0, Bs0, tid, lo, wmL, wnL, sw0, sw1, acc);
    b8_tile<0>(Ap, Bp, T + 1, As1, Bs1, As0, Bs0, tid, lo, wmL, wnL, sw0, sw1, acc);
  }
  b8_tile<1>(Ap, Bp, NKT - 2, As0, Bs0, As0, Bs0, tid, lo, wmL, wnL, sw0, sw1, acc);
  // MODE 2: computes tile 29 from buf1; stages tail A->As0 (mid) and tail B->Bs0 (end),
  // then vmcnt(0)+BAR -> tail resident.
  b8_tile<2>(Ap, Bp, NKT - 1, As1, Bs1, As0, Bs0, tid, lo, wmL, wnL, sw0, sw1, acc);

  // ---- tail compute: K columns 1920..1951, buf0 [256][32], swz s^(r&3) ----
  {
    const int swt = ((quad ^ (lo & 3)) << 3);
    bf16x8 a2[8], b2[4];
#pragma unroll
    for (int mf = 0; mf < 8; ++mf)
      a2[mf] = *(const bf16x8*)(As0 + ((wmL + mf * 16 + lo) << 5) + swt);
#pragma unroll
    for (int nf = 0; nf < 4; ++nf)
      b2[nf] = *(const bf16x8*)(Bs0 + ((wnL + nf * 16 + lo) << 5) + swt);
#pragma unroll
    for (int mf = 0; mf < 8; ++mf)
#pragma unroll
      for (int nf = 0; nf < 4; ++nf)
        acc[mf][nf] = __builtin_amdgcn_mfma_f32_16x16x32_bf16(a2[mf], b2[nf], acc[mf][nf], 0, 0, 0);
  }

  // ---- epilogue: gates via shfl butterfly -> h, c ----
#pragma unroll
  for (int nf = 0; nf < 4; ++nf) {
    int gn = n0 + wnL + nf * 16 + lo;   // permuted col: n = 4j + g
    int j2 = gn >> 2, g = gn & 3;
    float bias = (j2 < H) ? bvec[g * H + j2] : 0.f;
#pragma unroll
    for (int mf = 0; mf < 8; ++mf)
#pragma unroll
      for (int r = 0; r < 4; ++r) {
        float zs = acc[mf][nf][r] + bias;        // gate g
        float v1 = __shfl_xor(zs, 1);            // gate g^1
        float v2 = __shfl_xor(zs, 2);            // gate g^2
        float v3 = __shfl_xor(v1, 2);            // gate g^3
        if (g == r && j2 < H) {
          float zi, zf, zo, zu;
          { int t = 0 ^ g; zi = t == 0 ? zs : t == 1 ? v1 : t == 2 ? v2 : v3; }
          { int t = 1 ^ g; zf = t == 0 ? zs : t == 1 ? v1 : t == 2 ? v2 : v3; }
          { int t = 2 ^ g; zo = t == 0 ? zs : t == 1 ? v1 : t == 2 ? v2 : v3; }
          { int t = 3 ^ g; zu = t == 0 ? zs : t == 1 ? v1 : t == 2 ? v2 : v3; }
          float iv = 1.f / (1.f + __expf(-zi));
          float fv = 1.f / (1.f + __expf(-zf));
          float ov = 1.f / (1.f + __expf(-zo));
          float uv = tanhf(zu);
          int row = m0 + wmL + mf * 16 + quad * 4 + r;
          size_t oidx = (size_t)row * H + j2;
          float cp = c_prev[oidx];
          float cv = fv * cp + iv * uv;
          hout[oidx] = ov * tanhf(cv);
          cout[oidx] = cv;
        }
      }
  }
}

extern "C" void kernel_launch(void* const* d_in, const int* in_sizes, int n_in,
                              void* d_out, int out_size, void* d_ws, size_t ws_size,
                              hipStream_t stream) {
  const float* inputs = (const float*)d_in[0];
  const float* c_prev = (const float*)d_in[1];
  const float* h_prev = (const float*)d_in[2];
  const float* wx  = (const float*)d_in[3];
  const float* wh  = (const float*)d_in[4];
  const float* wmx = (const float*)d_in[5];
  const float* wmh = (const float*)d_in[6];
  const float* bv  = (const float*)d_in[7];
  const float* gx  = (const float*)d_in[8];
  const float* gh  = (const float*)d_in[9];
  const float* gmx = (const float*)d_in[10];
  const float* gmh = (const float*)d_in[11];

  char* ws = (char*)d_ws;
  float* s_wx  = (float*)(ws + OFF_SWX);
  float* s_wh  = (float*)(ws + OFF_SWH);
  float* s_wmx = (float*)(ws + OFF_SWMX);
  float* s_wmh = (float*)(ws + OFF_SWMH);
  float* wmxn  = (float*)(ws + OFF_WMXN);
  float* parts = (float*)(ws + OFF_PART);
  ushort_t* hbf   = (ushort_t*)(ws + OFF_HBF);
  ushort_t* m_ext = (ushort_t*)(ws + OFF_MEXT);
  ushort_t* wmhT  = (ushort_t*)(ws + OFF_WMHT);
  ushort_t* whxT  = (ushort_t*)(ws + OFF_WHXT);

  float* hout = (float*)d_out;
  float* cout = hout + (size_t)BATCH * H;

  static bool attr_set = false;
  if (!attr_set) {
    hipFuncSetAttribute(reinterpret_cast<const void*>(&gemmB8_kernel),
                        hipFuncAttributeMaxDynamicSharedMemorySize, 131072);
    attr_set = true;
  }

  colsum_partial_kernel<<<dim3(30, 4, 8), 256, 0, stream>>>(wx, wh, wmx, wmh, parts);
  scales_final_kernel<<<dim3(30, 4), 256, 0, stream>>>(parts, gx, gh, gmx, gmh,
                                                       s_wx, s_wh, s_wmx, s_wmh);
  cvt_h_kernel<<<62464, 256, 0, stream>>>(h_prev, hbf);
  wmxn_kernel<<<75, 256, 0, stream>>>(wmx, s_wmx, wmxn);
  wmhT_kernel<<<dim3(60, 61), 256, 0, stream>>>(wmh, s_wmh, wmhT);
  whxT_kernel<<<dim3(238, 61), 256, 0, stream>>>(wh, wx, s_wh, s_wx, whxT);
  mext_tail_kernel<<<1024, 256, 0, stream>>>(inputs, m_ext);
  whxT_tail_kernel<<<610, 256, 0, stream>>>(whxT);
  gemmA_kernel<<<dim3(64, 15), 256, 0, stream>>>(hbf, wmhT, inputs, wmxn, m_ext);
  gemmB8_kernel<<<dim3(960), 512, 131072, stream>>>(m_ext, whxT, bv, c_prev, hout, cout);
}

// Round 5
// 950.086 us; speedup vs baseline: 1.6935x; 1.6935x over previous
//
#include <hip/hip_runtime.h>

typedef unsigned short ushort_t;
typedef short bf16x8 __attribute__((ext_vector_type(8)));
typedef float f32x4 __attribute__((ext_vector_type(4)));

#define H 1900
#define FH 7600      // 4*H
#define BATCH 8192
#define KP 1952      // padded K stride for hbf/wmhT (gemmA operands)
#define NP_A 1920    // padded N for gemmA (m columns)
#define BK 32
#define KITERS (KP / BK)   // 61

// gemmB tiled-layout: panel = 128 rows; slab = one (128-row x 32-col) K-tile, 8KB
#define NSLAB 61           // 61*32 = 1952, no tail
#define SLAB_U 4096        // 128*32 ushorts per slab
#define PANEL_U 249856     // 61*4096 ushorts per panel

// ---- ws layout (bytes) ----
static const size_t OFF_SWX  = 0;          // 7600 f32
static const size_t OFF_SWH  = 32768;      // 7600 f32
static const size_t OFF_SWMX = 65536;      // 1900 f32
static const size_t OFF_SWMH = 73728;      // 1900 f32
static const size_t OFF_WMXN = 81920;      // 10*1920 f32 (pre-scaled wmx_n)
static const size_t OFF_PART = 163840;     // partial colsums
static const size_t OFF_HBF  = 786432;                   // h_prev bf16 [8192][1952] (KP layout)
static const size_t OFF_MEXT = OFF_HBF + 31981568;       // m_ext bf16 TILED: 64 panels * PANEL_U
static const size_t OFF_WMHT = OFF_MEXT + 31981568;      // wmh_n^T bf16 [1920][1952] (KP layout)
static const size_t OFF_WHXT = OFF_WMHT + 7495680;       // whxT bf16 TILED: 60 panels * PANEL_U
// end = OFF_WHXT + 29982720 ≈ 97.5 MB

// partial-sum sub-offsets (in floats, within OFF_PART)
#define PW_X  0
#define PW_H  60800
#define PW_MX 121600
#define PW_MH 136800

#define BAR() __builtin_amdgcn_s_barrier()
#define PRIO1 __builtin_amdgcn_s_setprio(1)
#define PRIO0 __builtin_amdgcn_s_setprio(0)
#define WAIT_VM(N) asm volatile("s_waitcnt vmcnt(" #N ")" ::: "memory")

__device__ __forceinline__ ushort_t f2bf(float x) {
  unsigned u = __float_as_uint(x);
  return (ushort_t)((u + 0x7fffu + ((u >> 16) & 1u)) >> 16);
}

// async global->LDS, 16 B per lane; LDS dest = wave-uniform base (+ lane*16 by HW)
__device__ __forceinline__ void gl_lds16(const ushort_t* g, ushort_t* lds) {
  __builtin_amdgcn_global_load_lds(
      (const __attribute__((address_space(1))) unsigned int*)(g),
      (__attribute__((address_space(3))) unsigned int*)(lds), 16, 0, 0);
}

// tiled-layout address (128-row panels, 32-col slabs, natural order within slab)
__device__ __forceinline__ size_t tiled_addr(int row, int col) {
  return (size_t)(row >> 7) * PANEL_U + (size_t)(col >> 5) * SLAB_U +
         (size_t)(row & 127) * 32 + (col & 31);
}

// ---------------- scales: per-column l2-norm partials, then gain*rsqrt ----------------
__global__ void colsum_partial_kernel(const float* __restrict__ wx, const float* __restrict__ wh,
                                      const float* __restrict__ wmx, const float* __restrict__ wmh,
                                      float* __restrict__ parts) {
  int c = blockIdx.x * 256 + threadIdx.x;
  int y = blockIdx.y, p = blockIdx.z;
  const float* W; int K, N; float* out;
  if (y == 0)      { W = wx;  K = 10;   N = FH; out = parts + PW_X  + (size_t)p * FH; }
  else if (y == 1) { W = wh;  K = 1900; N = FH; out = parts + PW_H  + (size_t)p * FH; }
  else if (y == 2) { W = wmx; K = 10;   N = H;  out = parts + PW_MX + (size_t)p * H;  }
  else             { W = wmh; K = 1900; N = H;  out = parts + PW_MH + (size_t)p * H;  }
  if (c >= N) return;
  int rp = (K + 7) / 8;
  int r0 = p * rp, r1 = r0 + rp; if (r1 > K) r1 = K;
  float s = 0.f;
  for (int r = r0; r < r1; ++r) { float v = W[(size_t)r * N + c]; s += v * v; }
  out[c] = s;
}

__global__ void scales_final_kernel(const float* __restrict__ parts,
                                    const float* __restrict__ gx, const float* __restrict__ gh,
                                    const float* __restrict__ gmx, const float* __restrict__ gmh,
                                    float* __restrict__ s_wx, float* __restrict__ s_wh,
                                    float* __restrict__ s_wmx, float* __restrict__ s_wmh) {
  int c = blockIdx.x * 256 + threadIdx.x;
  int y = blockIdx.y;
  const float* pp; int N; const float* g; float* out;
  if (y == 0)      { pp = parts + PW_X;  N = FH; g = gx;  out = s_wx;  }
  else if (y == 1) { pp = parts + PW_H;  N = FH; g = gh;  out = s_wh;  }
  else if (y == 2) { pp = parts + PW_MX; N = H;  g = gmx; out = s_wmx; }
  else             { pp = parts + PW_MH; N = H;  g = gmh; out = s_wmh; }
  if (c >= N) return;
  float s = 0.f;
  for (int p = 0; p < 8; ++p) s += pp[(size_t)p * N + c];
  out[c] = g[c] * rsqrtf(fmaxf(s, 1e-12f));
}

// ---------------- conversions ----------------
__global__ void cvt_h_kernel(const float* __restrict__ h_prev, ushort_t* __restrict__ hbf) {
  size_t idx = (size_t)blockIdx.x * 256 + threadIdx.x;   // < 8192*1952
  int row = (int)(idx / KP), col = (int)(idx % KP);
  float v = (col < H) ? h_prev[(size_t)row * H + col] : 0.f;
  hbf[idx] = f2bf(v);
}

__global__ void wmxn_kernel(const float* __restrict__ wmx, const float* __restrict__ s_wmx,
                            float* __restrict__ wmxn) {
  int idx = blockIdx.x * 256 + threadIdx.x;  // < 19200
  int i = idx / NP_A, j = idx - i * NP_A;
  wmxn[idx] = (j < H) ? wmx[i * H + j] * s_wmx[j] : 0.f;
}

// wmh [1900][1900] -> wmhT [1920][1952] bf16, transposed, pre-scaled (KP layout, gemmA operand)
__global__ void wmhT_kernel(const float* __restrict__ wmh, const float* __restrict__ s_wmh,
                            ushort_t* __restrict__ wmhT) {
  __shared__ float tile[32][33];
  int n0 = blockIdx.x * 32, k0 = blockIdx.y * 32;
  int tx = threadIdx.x & 31, ty = threadIdx.x >> 5;   // ty 0..7
#pragma unroll
  for (int it = 0; it < 4; ++it) {
    int k = k0 + ty + it * 8, n = n0 + tx;
    float v = (k < H && n < H) ? wmh[(size_t)k * H + n] : 0.f;
    tile[ty + it * 8][tx] = v;   // tile[k_local][n_local]
  }
  __syncthreads();
#pragma unroll
  for (int it = 0; it < 4; ++it) {
    int n = n0 + ty + it * 8, k = k0 + tx;
    float v = tile[tx][ty + it * 8];
    float s = (n < H) ? s_wmh[n] : 0.f;
    wmhT[(size_t)n * KP + k] = f2bf(v * s);
  }
}

// wh [1900][7600] + wx [10][7600] -> whxT TILED [60 panels]: row n=4j+g <- col c=g*1900+j,
// k<1900: wh_n ; 1920<=k<1930: wx_n ; else 0. Pre-scaled.
__global__ void whxT_kernel(const float* __restrict__ wh, const float* __restrict__ wx,
                            const float* __restrict__ s_wh, const float* __restrict__ s_wx,
                            ushort_t* __restrict__ whxT) {
  __shared__ float tile[32][33];
  int c0 = blockIdx.x * 32, k0 = blockIdx.y * 32;
  int tx = threadIdx.x & 31, ty = threadIdx.x >> 5;
#pragma unroll
  for (int it = 0; it < 4; ++it) {
    int k = k0 + ty + it * 8, c = c0 + tx;
    float v = 0.f;
    if (c < FH) {
      if (k < H) v = wh[(size_t)k * FH + c] * s_wh[c];
      else if (k >= NP_A && k < NP_A + 10) v = wx[(size_t)(k - NP_A) * FH + c] * s_wx[c];
    }
    tile[ty + it * 8][tx] = v;   // tile[k_local][c_local]
  }
  __syncthreads();
#pragma unroll
  for (int it = 0; it < 4; ++it) {
    int c = c0 + ty + it * 8, k = k0 + tx;
    if (c < FH) {
      int g = c / H; int j = c - g * H; int n = 4 * j + g;
      whxT[tiled_addr(n, k)] = f2bf(tile[tx][ty + it * 8]);
    }
  }
}

__global__ void mext_tail_kernel(const float* __restrict__ inputs, ushort_t* __restrict__ m_ext) {
  int idx = blockIdx.x * 256 + threadIdx.x;   // < 8192*32
  int row = idx >> 5, c = idx & 31;
  float v = (c < 10) ? inputs[(size_t)row * 10 + c] : 0.f;
  m_ext[tiled_addr(row, 1920 + c)] = f2bf(v);
}

__global__ void whxT_tail_kernel(ushort_t* __restrict__ whxT) {
  int idx = blockIdx.x * 256 + threadIdx.x;   // < 80*1952
  int n = 7600 + idx / 1952, k = idx % 1952;
  whxT[tiled_addr(n, k)] = 0;
}

// ============ gemmA core: 128x128 tile, BK=32, single-buffer (round-0 proven) ============
__device__ __forceinline__ void gemm_tile128(const ushort_t* __restrict__ Ag,
                                             const ushort_t* __restrict__ Bg,
                                             int m0, int n0,
                                             ushort_t* As, ushort_t* Bs,
                                             f32x4 acc[4][4]) {
  const int tid = threadIdx.x;
  const int lane = tid & 63;
  const int quad = lane >> 4;
  const int lo = lane & 15;
  const int wave = tid >> 6;
  const int wm = (wave & 1) << 6;
  const int wn = (wave >> 1) << 6;
  const int sw = (lo >> 1) & 3;

  const int cr = lane >> 2;
  const int hg = (lane & 3) ^ ((lane >> 3) & 3);
  const int r0 = wave * 16 + cr;
  const int r1 = 64 + wave * 16 + cr;
  const ushort_t* gA0 = Ag + (size_t)(m0 + r0) * KP + hg * 8;
  const ushort_t* gA1 = Ag + (size_t)(m0 + r1) * KP + hg * 8;
  const ushort_t* gB0 = Bg + (size_t)(n0 + r0) * KP + hg * 8;
  const ushort_t* gB1 = Bg + (size_t)(n0 + r1) * KP + hg * 8;
  ushort_t* lA0 = As + (wave * 16) * BK;
  ushort_t* lA1 = As + (64 + wave * 16) * BK;
  ushort_t* lB0 = Bs + (wave * 16) * BK;
  ushort_t* lB1 = Bs + (64 + wave * 16) * BK;

  for (int kt = 0; kt < KITERS; ++kt) {
    __syncthreads();
    gl_lds16(gA0, lA0);
    gl_lds16(gA1, lA1);
    gl_lds16(gB0, lB0);
    gl_lds16(gB1, lB1);
    __syncthreads();
    bf16x8 af[4], bfv[4];
#pragma unroll
    for (int mf = 0; mf < 4; ++mf)
      af[mf] = *(const bf16x8*)(As + (wm + mf * 16 + lo) * BK + ((quad ^ sw) << 3));
#pragma unroll
    for (int nf = 0; nf < 4; ++nf)
      bfv[nf] = *(const bf16x8*)(Bs + (wn + nf * 16 + lo) * BK + ((quad ^ sw) << 3));
#pragma unroll
    for (int mf = 0; mf < 4; ++mf)
#pragma unroll
      for (int nf = 0; nf < 4; ++nf)
        acc[mf][nf] = __builtin_amdgcn_mfma_f32_16x16x32_bf16(af[mf], bfv[nf], acc[mf][nf], 0, 0, 0);
    gA0 += BK; gA1 += BK; gB0 += BK; gB1 += BK;
  }
}

// GEMM-A: P = h_prev_bf @ wmh_n^T ; epilogue m = (inputs·wmx_n) * P -> m_ext (TILED)
__global__ void __launch_bounds__(256) gemmA_kernel(const ushort_t* __restrict__ hbf,
                                                    const ushort_t* __restrict__ wmhT,
                                                    const float* __restrict__ inputs,
                                                    const float* __restrict__ wmxn,
                                                    ushort_t* __restrict__ m_ext) {
  __shared__ __align__(16) char smem[16384];
  ushort_t* As = (ushort_t*)smem;
  ushort_t* Bs = (ushort_t*)(smem + 8192);
  f32x4 acc[4][4];
  f32x4 zv = {0.f, 0.f, 0.f, 0.f};
#pragma unroll
  for (int a = 0; a < 4; ++a)
#pragma unroll
    for (int bq = 0; bq < 4; ++bq) acc[a][bq] = zv;
  int m0 = blockIdx.x * 128, n0 = blockIdx.y * 128;
  gemm_tile128(hbf, wmhT, m0, n0, As, Bs, acc);
  __syncthreads();
  float* inL  = (float*)smem;            // [128][10]
  float* wmxL = (float*)(smem + 5120);   // [10][128]
  for (int t = threadIdx.x; t < 1280; t += 256) {
    int r = t / 10, i = t - r * 10;
    inL[t] = inputs[(size_t)(m0 + r) * 10 + i];
  }
  for (int t = threadIdx.x; t < 1280; t += 256) {
    int i = t >> 7, c = t & 127;
    wmxL[t] = wmxn[i * NP_A + n0 + c];
  }
  __syncthreads();
  const int lane = threadIdx.x & 63, quad = lane >> 4, lo = lane & 15;
  const int wave = threadIdx.x >> 6, wm = (wave & 1) << 6, wn = (wave >> 1) << 6;
#pragma unroll
  for (int mf = 0; mf < 4; ++mf)
#pragma unroll
    for (int r = 0; r < 4; ++r) {
      int rl = wm + mf * 16 + quad * 4 + r;
      float inrow[10];
#pragma unroll
      for (int i = 0; i < 10; ++i) inrow[i] = inL[rl * 10 + i];
#pragma unroll
      for (int nf = 0; nf < 4; ++nf) {
        int cl = wn + nf * 16 + lo;
        float mx = 0.f;
#pragma unroll
        for (int i = 0; i < 10; ++i) mx += inrow[i] * wmxL[i * 128 + cl];
        float mv = acc[mf][nf][r] * mx;
        m_ext[tiled_addr(m0 + rl, n0 + cl)] = f2bf(mv);
      }
    }
}

// ====== gemmB: 128x128 tile, BK=32, 4 waves, triple-buffered counted prefetch, 3 blk/CU =====
// Slab (128x32, 8KB) staged as one contiguous burst; stored 16B-slot s of row r holds
// global slot s^(r&3) (source-side swizzle, rule #21). Reads use slot quad^(lo&3).
// Step t: issue stage(t+2) -> buf[(t+2)%3]  (4 gl_lds/thread)
//         read buf[t%3] (8 ds_read_b128) ; 16 MFMA
//         vmcnt(4)  -> t+1's stages complete (t+2's 4 stay in flight) ; BAR
// Hazard: buf[(t+2)%3] was read at step t-1; readers drained (lgkm before MFMA) + BAR. OK.

__device__ __forceinline__ void stage_slab(const ushort_t* __restrict__ Gp, int slab,
                                           ushort_t* L, int tid) {
  const int wave = tid >> 6;
#pragma unroll
  for (int q = 0; q < 2; ++q) {
    const int idx = q * 256 + tid;          // 0..511 lane-slots (128 rows x 4 slots)
    const int r = idx >> 2, s = idx & 3;
    const int gs = s ^ (r & 3);
    gl_lds16(Gp + (size_t)slab * SLAB_U + r * 32 + gs * 8,
             L + (size_t)(q * 256 + wave * 64) * 8);
  }
}

template <int MODE>   // 0 = steady (stage t+2, vmcnt(4)); 1 = vmcnt(0); 2 = final (no wait)
__device__ __forceinline__ void b5_step(const ushort_t* __restrict__ Ap,
                                        const ushort_t* __restrict__ Bp, int t,
                                        ushort_t* Acur, ushort_t* Bcur,
                                        ushort_t* Astg, ushort_t* Bstg,
                                        int tid, int lo, int quad, int wm, int wn,
                                        f32x4 acc[4][4]) {
  if (MODE == 0) {
    stage_slab(Ap, t + 2, Astg, tid);
    stage_slab(Bp, t + 2, Bstg, tid);
  }
  const int k0 = (quad ^ (lo & 3)) << 3;
  bf16x8 af[4], bfv[4];
#pragma unroll
  for (int mf = 0; mf < 4; ++mf)
    af[mf] = *(const bf16x8*)(Acur + ((wm + mf * 16 + lo) << 5) + k0);
#pragma unroll
  for (int nf = 0; nf < 4; ++nf)
    bfv[nf] = *(const bf16x8*)(Bcur + ((wn + nf * 16 + lo) << 5) + k0);
  PRIO1;
#pragma unroll
  for (int mf = 0; mf < 4; ++mf)
#pragma unroll
    for (int nf = 0; nf < 4; ++nf)
      acc[mf][nf] = __builtin_amdgcn_mfma_f32_16x16x32_bf16(af[mf], bfv[nf], acc[mf][nf], 0, 0, 0);
  PRIO0;
  if (MODE == 0) { WAIT_VM(4); BAR(); }
  else if (MODE == 1) { WAIT_VM(0); BAR(); }
}

__global__ void __launch_bounds__(256, 3)
gemmB5_kernel(const ushort_t* __restrict__ mext, const ushort_t* __restrict__ whxT,
              const float* __restrict__ bvec, const float* __restrict__ c_prev,
              float* __restrict__ hout, float* __restrict__ cout) {
  __shared__ __align__(16) char smem[49152];   // 3 x (A 8KB + B 8KB)
  ushort_t* As[3] = {(ushort_t*)smem, (ushort_t*)(smem + 16384), (ushort_t*)(smem + 32768)};
  ushort_t* Bs[3] = {(ushort_t*)(smem + 8192), (ushort_t*)(smem + 24576),
                     (ushort_t*)(smem + 40960)};

  const int tid = threadIdx.x;
  const int lane = tid & 63;
  const int lo = lane & 15, quad = lane >> 4;
  const int wave = tid >> 6;
  const int wm = (wave & 1) << 6;
  const int wn = (wave >> 1) << 6;

  // XCD panel ownership: 3840 blocks = 8 XCDs x 480. XCD x owns mt in [8x, 8x+8).
  // j = bid>>3: mt_local = j&7, nt = j>>3. Concurrent ~96 blk/XCD = 8mt x 12nt:
  // A panel L2-shared 12x, B panel 8x.
  int bid = blockIdx.x;
  int xcd = bid & 7, jj = bid >> 3;           // jj in [0,480)
  int mt = (xcd << 3) | (jj & 7);             // [0,64)
  int nt = jj >> 3;                           // [0,60)
  int m0 = mt << 7, n0 = nt << 7;

  f32x4 acc[4][4];
  f32x4 zv = {0.f, 0.f, 0.f, 0.f};
#pragma unroll
  for (int a = 0; a < 4; ++a)
#pragma unroll
    for (int bq = 0; bq < 4; ++bq) acc[a][bq] = zv;

  const ushort_t* Ap = mext + (size_t)mt * PANEL_U;
  const ushort_t* Bp = whxT + (size_t)nt * PANEL_U;

  // prologue: slab0 -> buf0, slab1 -> buf1; slab1's 4 loads stay in flight
  stage_slab(Ap, 0, As[0], tid);
  stage_slab(Bp, 0, Bs[0], tid);
  stage_slab(Ap, 1, As[1], tid);
  stage_slab(Bp, 1, Bs[1], tid);
  WAIT_VM(4);
  BAR();

  // steps 0..53 (18 unrolled triples), stages reach slab 55
  for (int t = 0; t < 54; t += 3) {
    b5_step<0>(Ap, Bp, t,     As[0], Bs[0], As[2], Bs[2], tid, lo, quad, wm, wn, acc);
    b5_step<0>(Ap, Bp, t + 1, As[1], Bs[1], As[0], Bs[0], tid, lo, quad, wm, wn, acc);
    b5_step<0>(Ap, Bp, t + 2, As[2], Bs[2], As[1], Bs[1], tid, lo, quad, wm, wn, acc);
  }
  // steps 54..58 full (stage 56..60), 59 drain, 60 final
  b5_step<0>(Ap, Bp, 54, As[0], Bs[0], As[2], Bs[2], tid, lo, quad, wm, wn, acc);
  b5_step<0>(Ap, Bp, 55, As[1], Bs[1], As[0], Bs[0], tid, lo, quad, wm, wn, acc);
  b5_step<0>(Ap, Bp, 56, As[2], Bs[2], As[1], Bs[1], tid, lo, quad, wm, wn, acc);
  b5_step<0>(Ap, Bp, 57, As[0], Bs[0], As[2], Bs[2], tid, lo, quad, wm, wn, acc);
  b5_step<0>(Ap, Bp, 58, As[1], Bs[1], As[0], Bs[0], tid, lo, quad, wm, wn, acc);
  b5_step<1>(Ap, Bp, 59, As[2], Bs[2], nullptr, nullptr, tid, lo, quad, wm, wn, acc);
  b5_step<2>(Ap, Bp, 60, As[0], Bs[0], nullptr, nullptr, tid, lo, quad, wm, wn, acc);

  // ---- epilogue: gates via shfl butterfly -> h, c ----
#pragma unroll
  for (int nf = 0; nf < 4; ++nf) {
    int gn = n0 + wn + nf * 16 + lo;   // permuted col: n = 4j + g
    int j2 = gn >> 2, g = gn & 3;
    float bias = (j2 < H) ? bvec[g * H + j2] : 0.f;
#pragma unroll
    for (int mf = 0; mf < 4; ++mf)
#pragma unroll
      for (int r = 0; r < 4; ++r) {
        float zs = acc[mf][nf][r] + bias;        // gate g
        float v1 = __shfl_xor(zs, 1);            // gate g^1
        float v2 = __shfl_xor(zs, 2);            // gate g^2
        float v3 = __shfl_xor(v1, 2);            // gate g^3
        if (g == r && j2 < H) {
          float zi, zf, zo, zu;
          { int t = 0 ^ g; zi = t == 0 ? zs : t == 1 ? v1 : t == 2 ? v2 : v3; }
          { int t = 1 ^ g; zf = t == 0 ? zs : t == 1 ? v1 : t == 2 ? v2 : v3; }
          { int t = 2 ^ g; zo = t == 0 ? zs : t == 1 ? v1 : t == 2 ? v2 : v3; }
          { int t = 3 ^ g; zu = t == 0 ? zs : t == 1 ? v1 : t == 2 ? v2 : v3; }
          float iv = 1.f / (1.f + __expf(-zi));
          float fv = 1.f / (1.f + __expf(-zf));
          float ov = 1.f / (1.f + __expf(-zo));
          float uv = tanhf(zu);
          int row = m0 + wm + mf * 16 + quad * 4 + r;
          size_t oidx = (size_t)row * H + j2;
          float cp = c_prev[oidx];
          float cv = fv * cp + iv * uv;
          hout[oidx] = ov * tanhf(cv);
          cout[oidx] = cv;
        }
      }
  }
}

extern "C" void kernel_launch(void* const* d_in, const int* in_sizes, int n_in,
                              void* d_out, int out_size, void* d_ws, size_t ws_size,
                              hipStream_t stream) {
  const float* inputs = (const float*)d_in[0];
  const float* c_prev = (const float*)d_in[1];
  const float* h_prev = (const float*)d_in[2];
  const float* wx  = (const float*)d_in[3];
  const float* wh  = (const float*)d_in[4];
  const float* wmx = (const float*)d_in[5];
  const float* wmh = (const float*)d_in[6];
  const float* bv  = (const float*)d_in[7];
  const float* gx  = (const float*)d_in[8];
  const float* gh  = (const float*)d_in[9];
  const float* gmx = (const float*)d_in[10];
  const float* gmh = (const float*)d_in[11];

  char* ws = (char*)d_ws;
  float* s_wx  = (float*)(ws + OFF_SWX);
  float* s_wh  = (float*)(ws + OFF_SWH);
  float* s_wmx = (float*)(ws + OFF_SWMX);
  float* s_wmh = (float*)(ws + OFF_SWMH);
  float* wmxn  = (float*)(ws + OFF_WMXN);
  float* parts = (float*)(ws + OFF_PART);
  ushort_t* hbf   = (ushort_t*)(ws + OFF_HBF);
  ushort_t* m_ext = (ushort_t*)(ws + OFF_MEXT);
  ushort_t* wmhT  = (ushort_t*)(ws + OFF_WMHT);
  ushort_t* whxT  = (ushort_t*)(ws + OFF_WHXT);

  float* hout = (float*)d_out;
  float* cout = hout + (size_t)BATCH * H;

  colsum_partial_kernel<<<dim3(30, 4, 8), 256, 0, stream>>>(wx, wh, wmx, wmh, parts);
  scales_final_kernel<<<dim3(30, 4), 256, 0, stream>>>(parts, gx, gh, gmx, gmh,
                                                       s_wx, s_wh, s_wmx, s_wmh);
  cvt_h_kernel<<<62464, 256, 0, stream>>>(h_prev, hbf);
  wmxn_kernel<<<75, 256, 0, stream>>>(wmx, s_wmx, wmxn);
  wmhT_kernel<<<dim3(60, 61), 256, 0, stream>>>(wmh, s_wmh, wmhT);
  whxT_kernel<<<dim3(238, 61), 256, 0, stream>>>(wh, wx, s_wh, s_wx, whxT);
  mext_tail_kernel<<<1024, 256, 0, stream>>>(inputs, m_ext);
  whxT_tail_kernel<<<610, 256, 0, stream>>>(whxT);
  gemmA_kernel<<<dim3(64, 15), 256, 0, stream>>>(hbf, wmhT, inputs, wmxn, m_ext);
  gemmB5_kernel<<<3840, 256, 0, stream>>>(m_ext, whxT, bv, c_prev, hout, cout);
}